// Round 5
// baseline (329.143 us; speedup 1.0000x reference)
//
#include <hip/hip_runtime.h>
#include <math.h>

#define Nn 10000
#define Ee 160000
#define NBb 8

// Static device scratch — slot-ordered (CSR order) edge data for streaming reads.
__device__ __align__(16) float g_shc[Ee * 12];  // [slot][12] (9 used, pad to 48B)
__device__ __align__(16) float g_Rc[Ee * 64];   // [slot][64]
__device__ int   g_src[Ee];                     // [slot] sender node
__device__ float g_h[2][Nn * 64];
__device__ float g_h1[Nn * 64];
__device__ float g_hsc[Nn * 64];
__device__ int   g_deg[Nn];
__device__ int   g_offs[Nn + 1];
__device__ int   g_cursor[Nn];
__device__ int   g_csr[Ee];
__device__ float g_W1T[64 * NBb];               // W_r1 transposed: [j][k]

__global__ __launch_bounds__(256) void k_zero(float* out, int out_size) {
    int i = blockIdx.x * 256 + threadIdx.x;
    if (i < out_size) out[i] = 0.0f;
    if (i < Nn) { g_deg[i] = 0; g_cursor[i] = 0; }
}

// degree count; block 0 also transposes W_r1 -> g_W1T (runs before k_edge)
__global__ __launch_bounds__(256) void k_deg(const int* __restrict__ eidx,
                                             const float* __restrict__ Wr1) {
    int e = blockIdx.x * 256 + threadIdx.x;
    if (e < Ee) atomicAdd(&g_deg[eidx[Ee + e]], 1);
    if (blockIdx.x == 0) {
        for (int i = threadIdx.x; i < 64 * NBb; i += 256) {
            int k = i >> 6, j = i & 63;  // Wr1[k][j]
            g_W1T[j * NBb + k] = Wr1[i];
        }
    }
}

__global__ __launch_bounds__(1024) void k_scan() {
    __shared__ int part[1024];
    int t = threadIdx.x;
    const int CH = (Nn + 1023) / 1024;  // 10
    int st = t * CH;
    int en = st + CH; if (en > Nn) en = Nn;
    int s = 0;
    for (int i = st; i < en; i++) s += g_deg[i];
    part[t] = s;
    __syncthreads();
    for (int d = 1; d < 1024; d <<= 1) {
        int v = (t >= d) ? part[t - d] : 0;
        __syncthreads();
        part[t] += v;
        __syncthreads();
    }
    int base = (t == 0) ? 0 : part[t - 1];
    for (int i = st; i < en; i++) { g_offs[i] = base; base += g_deg[i]; }
    if (t == 1023) g_offs[Nn] = part[1023];
}

__global__ __launch_bounds__(256) void k_fill(const int* __restrict__ eidx) {
    int e = blockIdx.x * 256 + threadIdx.x;
    if (e >= Ee) return;
    int r = eidx[Ee + e];
    int p = g_offs[r] + atomicAdd(&g_cursor[r], 1);
    g_csr[p] = e;
}

// Per-edge geometry + radial MLP, written in CSR slot order.
// Weights read via wave-uniform indices -> scalar loads (s_load), no LDS.
__global__ __launch_bounds__(256) void k_edge(const float* __restrict__ pos,
                                              const float* __restrict__ br1,
                                              const float* __restrict__ Wr2,
                                              const int* __restrict__ eidx) {
    int s = blockIdx.x * 256 + threadIdx.x;
    if (s >= Ee) return;
    int e = g_csr[s];
    int snd = eidx[e];
    int rcv = eidx[Ee + e];
    float vx = pos[3 * rcv + 0] - pos[3 * snd + 0];
    float vy = pos[3 * rcv + 1] - pos[3 * snd + 1];
    float vz = pos[3 * rcv + 2] - pos[3 * snd + 2];
    float r = sqrtf(vx * vx + vy * vy + vz * vz);
    float inv = __builtin_amdgcn_rcpf(fmaxf(r, 1e-9f));
    float x = vx * inv, y = vy * inv, z = vz * inv;
    const float s3 = 1.7320508f;
    float4* shp = (float4*)(g_shc + (size_t)s * 12);
    shp[0] = make_float4(1.0f, x, y, z);
    shp[1] = make_float4(s3 * x * y, s3 * y * z, 0.5f * (3.0f * z * z - 1.0f), s3 * x * z);
    shp[2] = make_float4(0.5f * s3 * (x * x - y * y), 0.0f, 0.0f, 0.0f);
    g_src[s] = snd;

    float xx = r * 0.2f;
    float env = 0.0f;
    if (xx < 1.0f) {
        float x2 = xx * xx;
        float x6 = x2 * x2 * x2;
        float x7 = x6 * xx;
        float x8 = x7 * xx;
        env = 1.0f - 28.0f * x6 + 48.0f * x7 - 21.0f * x8;
    }
    const float pref = 0.63245553f;  // sqrt(2/R_MAX)
    const float PI_F = 3.14159265358979f;
    float fac = pref * inv * env;
    float ef[NBb];
#pragma unroll
    for (int k = 0; k < NBb; k++)
        ef[k] = fac * __sinf((float)(k + 1) * PI_F * r * 0.2f);

    float4 acc[16];
#pragma unroll
    for (int c = 0; c < 16; c++) acc[c] = make_float4(0.f, 0.f, 0.f, 0.f);

    for (int j = 0; j < 64; j++) {
        float a = br1[j];
#pragma unroll
        for (int k = 0; k < NBb; k++) a += ef[k] * g_W1T[j * NBb + k];
        // silu via fast intrinsics (1 exp + 1 rcp)
        a = a * __builtin_amdgcn_rcpf(1.0f + __expf(-a));
        const float* __restrict__ w2 = Wr2 + j * 64;
#pragma unroll
        for (int c = 0; c < 16; c++) {
            acc[c].x += a * w2[4 * c + 0];
            acc[c].y += a * w2[4 * c + 1];
            acc[c].z += a * w2[4 * c + 2];
            acc[c].w += a * w2[4 * c + 3];
        }
    }
    float4* dst = (float4*)(g_Rc + (size_t)s * 64);
#pragma unroll
    for (int c = 0; c < 16; c++) dst[c] = acc[c];
}

__global__ __launch_bounds__(256) void k_hinit(const float* __restrict__ W_embed,
                                               const int* __restrict__ atom_types) {
    int i = blockIdx.x * 256 + threadIdx.x;
    if (i >= Nn * 64) return;
    int n = i >> 6, c = i & 63;
    g_h[0][i] = W_embed[atom_types[n] * 64 + c];
}

__global__ __launch_bounds__(256) void k_lin(const float* __restrict__ Wup,
                                             const float* __restrict__ Wsc, int l) {
    __shared__ float sU[4096];
    __shared__ float sS[4096];
    int t = threadIdx.x;
    for (int i = t; i < 4096; i += 256) { sU[i] = Wup[i]; sS[i] = Wsc[i]; }
    __syncthreads();
    int node = blockIdx.x * 4 + (t >> 6);
    int lane = t & 63;
    const float* hin = g_h[l & 1];
    float hv = hin[node * 64 + lane];
    float a1 = 0.0f, a2 = 0.0f;
#pragma unroll
    for (int k = 0; k < 64; k++) {
        float hk = __shfl(hv, k, 64);
        a1 += hk * sU[k * 64 + lane];
        a2 += hk * sS[k * 64 + lane];
    }
    g_h1[node * 64 + lane] = a1;
    g_hsc[node * 64 + lane] = a2;
}

// Streaming gather, 8-wide batched loads to expose memory-level parallelism:
// all 8 src indices load first (mergeable into s_load_dwordx8), then 8
// independent R rows + 8 h1 gathers + 8 sh rows are in flight together.
__global__ __launch_bounds__(256) void k_node(const float* __restrict__ Wprod,
                                              const float* __restrict__ wro,
                                              const int* __restrict__ batch,
                                              int l, float* __restrict__ out) {
    __shared__ float sP[4096];
    int t = threadIdx.x;
    for (int i = t; i < 4096; i += 256) sP[i] = Wprod[i];
    __syncthreads();
    int node = blockIdx.x * 4 + (t >> 6);
    int lane = t & 63;
    int beg = __builtin_amdgcn_readfirstlane(g_offs[node]);
    int en  = __builtin_amdgcn_readfirstlane(g_offs[node + 1]);
    float A[9];
#pragma unroll
    for (int m = 0; m < 9; m++) A[m] = 0.0f;

    int j = beg;
    for (; j + 8 <= en; j += 8) {
        int srcs[8];
#pragma unroll
        for (int k = 0; k < 8; k++)
            srcs[k] = __builtin_amdgcn_readfirstlane(g_src[j + k]);
        float rv[8];
#pragma unroll
        for (int k = 0; k < 8; k++)
            rv[k] = g_Rc[(size_t)(j + k) * 64 + lane];
        float hv[8];
#pragma unroll
        for (int k = 0; k < 8; k++)
            hv[k] = g_h1[srcs[k] * 64 + lane];
        float4 sh0[8], sh1[8], sh2[8];
#pragma unroll
        for (int k = 0; k < 8; k++) {
            const float4* p = (const float4*)(g_shc + (size_t)(j + k) * 12);
            sh0[k] = p[0]; sh1[k] = p[1]; sh2[k] = p[2];
        }
#pragma unroll
        for (int k = 0; k < 8; k++) {
            float tv = rv[k] * hv[k];
            A[0] += sh0[k].x * tv; A[1] += sh0[k].y * tv;
            A[2] += sh0[k].z * tv; A[3] += sh0[k].w * tv;
            A[4] += sh1[k].x * tv; A[5] += sh1[k].y * tv;
            A[6] += sh1[k].z * tv; A[7] += sh1[k].w * tv;
            A[8] += sh2[k].x * tv;
        }
    }
    for (; j < en; j++) {
        int s0 = __builtin_amdgcn_readfirstlane(g_src[j]);
        float tv = g_Rc[(size_t)j * 64 + lane] * g_h1[s0 * 64 + lane];
        const float4* p0 = (const float4*)(g_shc + (size_t)j * 12);
        float4 u0 = p0[0], u1 = p0[1], u2 = p0[2];
        A[0] += u0.x * tv; A[1] += u0.y * tv; A[2] += u0.z * tv;
        A[3] += u0.w * tv; A[4] += u1.x * tv; A[5] += u1.y * tv;
        A[6] += u1.z * tv; A[7] += u1.w * tv; A[8] += u2.x * tv;
    }

    const float invn = 1.0f / 16.0f;  // AVG_NEI
    float q = A[0] * invn;
#pragma unroll
    for (int m = 0; m < 9; m++) {
        float a = A[m] * invn;
        q += a * a;
    }
    float hn = g_hsc[node * 64 + lane];
#pragma unroll
    for (int k = 0; k < 64; k++) {
        float qk = __shfl(q, k, 64);
        hn += qk * sP[k * 64 + lane];
    }
    float* hout = g_h[(l + 1) & 1];
    hout[node * 64 + lane] = hn;
    float v = hn * wro[lane];
#pragma unroll
    for (int off = 32; off > 0; off >>= 1) v += __shfl_down(v, off, 64);
    if (lane == 0) atomicAdd(&out[batch[node]], v);
}

extern "C" void kernel_launch(void* const* d_in, const int* in_sizes, int n_in,
                              void* d_out, int out_size, void* d_ws, size_t ws_size,
                              hipStream_t stream) {
    const float* pos     = (const float*)d_in[0];
    const float* W_embed = (const float*)d_in[1];
    const float* W_r1    = (const float*)d_in[2];
    const float* b_r1    = (const float*)d_in[3];
    const float* W_r2    = (const float*)d_in[4];
    const float* W_up    = (const float*)d_in[5];
    const float* W_sc    = (const float*)d_in[6];
    const float* W_prod  = (const float*)d_in[7];
    const float* w_ro    = (const float*)d_in[8];
    const int* atom_types = (const int*)d_in[9];
    const int* eidx       = (const int*)d_in[10];
    const int* batch      = (const int*)d_in[11];
    float* out = (float*)d_out;

    k_zero<<<(Nn + 255) / 256, 256, 0, stream>>>(out, out_size);
    k_deg<<<Ee / 256, 256, 0, stream>>>(eidx, W_r1);
    k_scan<<<1, 1024, 0, stream>>>();
    k_fill<<<Ee / 256, 256, 0, stream>>>(eidx);
    k_edge<<<Ee / 256, 256, 0, stream>>>(pos, b_r1, W_r2, eidx);
    k_hinit<<<(Nn * 64) / 256, 256, 0, stream>>>(W_embed, atom_types);
    for (int l = 0; l < 2; l++) {
        k_lin<<<Nn / 4, 256, 0, stream>>>(W_up + l * 4096, W_sc + l * 4096, l);
        k_node<<<Nn / 4, 256, 0, stream>>>(W_prod + l * 4096, w_ro + l * 64, batch, l, out);
    }
}

// Round 6
// 320.486 us; speedup vs baseline: 1.0270x; 1.0270x over previous
//
#include <hip/hip_runtime.h>
#include <math.h>

#define Nn 10000
#define Ee 160000
#define NBb 8
#define CSRMAX 230400  // Ee + 8-padding slack (<= 7 per node), 900*256

// Static device scratch.
// sh record per slot: [0..3]=sh0..3, [4..7]=sh4..7, [8]=sh8, [9]=src bits, [10,11]=0
__device__ __align__(16) float g_shc[(size_t)CSRMAX * 12];
// R interleaved by 4 slots: g_R4[(slot>>2)*256 + chan*4 + (slot&3)]
__device__ __align__(16) float g_R4[(size_t)CSRMAX * 64];
__device__ float g_h[2][Nn * 64];
__device__ float g_h1[Nn * 64];
__device__ float g_hsc[Nn * 64];
__device__ int   g_deg[Nn];
__device__ int   g_offs[Nn + 1];
__device__ int   g_cursor[Nn];
__device__ int   g_csr[CSRMAX];
__device__ float g_W1T[64 * NBb];  // W_r1 transposed: [j][k]

__global__ __launch_bounds__(256) void k_zero(float* out, int out_size) {
    int i = blockIdx.x * 256 + threadIdx.x;
    if (i < CSRMAX) g_csr[i] = -1;
    if (i < out_size) out[i] = 0.0f;
    if (i < Nn) { g_deg[i] = 0; g_cursor[i] = 0; }
}

// degree count; block 0 also transposes W_r1 -> g_W1T (runs before k_edge)
__global__ __launch_bounds__(256) void k_deg(const int* __restrict__ eidx,
                                             const float* __restrict__ Wr1) {
    int e = blockIdx.x * 256 + threadIdx.x;
    if (e < Ee) atomicAdd(&g_deg[eidx[Ee + e]], 1);
    if (blockIdx.x == 0) {
        for (int i = threadIdx.x; i < 64 * NBb; i += 256) {
            int k = i >> 6, j = i & 63;  // Wr1[k][j]
            g_W1T[j * NBb + k] = Wr1[i];
        }
    }
}

// prefix sum of degrees padded up to multiples of 8
__global__ __launch_bounds__(1024) void k_scan() {
    __shared__ int part[1024];
    int t = threadIdx.x;
    const int CH = (Nn + 1023) / 1024;  // 10
    int st = t * CH;
    int en = st + CH; if (en > Nn) en = Nn;
    int s = 0;
    for (int i = st; i < en; i++) s += (g_deg[i] + 7) & ~7;
    part[t] = s;
    __syncthreads();
    for (int d = 1; d < 1024; d <<= 1) {
        int v = (t >= d) ? part[t - d] : 0;
        __syncthreads();
        part[t] += v;
        __syncthreads();
    }
    int base = (t == 0) ? 0 : part[t - 1];
    for (int i = st; i < en; i++) { g_offs[i] = base; base += (g_deg[i] + 7) & ~7; }
    if (t == 1023) g_offs[Nn] = part[1023];
}

__global__ __launch_bounds__(256) void k_fill(const int* __restrict__ eidx) {
    int e = blockIdx.x * 256 + threadIdx.x;
    if (e >= Ee) return;
    int r = eidx[Ee + e];
    int p = g_offs[r] + atomicAdd(&g_cursor[r], 1);
    g_csr[p] = e;
}

// Per-slot: geometry + radial MLP -> R (interleaved-4) + sh/src record.
// Pad slots (csr == -1) get a zero sh record so they contribute nothing.
__global__ __launch_bounds__(256) void k_edge(const float* __restrict__ pos,
                                              const float* __restrict__ br1,
                                              const float* __restrict__ Wr2,
                                              const int* __restrict__ eidx) {
    int s = blockIdx.x * 256 + threadIdx.x;
    if (s >= CSRMAX) return;
    int e = g_csr[s];
    float4* shp = (float4*)(g_shc + (size_t)s * 12);
    if (e < 0) {
        shp[0] = make_float4(0.f, 0.f, 0.f, 0.f);
        shp[1] = make_float4(0.f, 0.f, 0.f, 0.f);
        shp[2] = make_float4(0.f, 0.f, 0.f, 0.f);  // src = 0
        return;
    }
    int snd = eidx[e];
    int rcv = eidx[Ee + e];
    float vx = pos[3 * rcv + 0] - pos[3 * snd + 0];
    float vy = pos[3 * rcv + 1] - pos[3 * snd + 1];
    float vz = pos[3 * rcv + 2] - pos[3 * snd + 2];
    float r = sqrtf(vx * vx + vy * vy + vz * vz);
    float inv = __builtin_amdgcn_rcpf(fmaxf(r, 1e-9f));
    float x = vx * inv, y = vy * inv, z = vz * inv;
    const float s3 = 1.7320508f;
    shp[0] = make_float4(1.0f, x, y, z);
    shp[1] = make_float4(s3 * x * y, s3 * y * z, 0.5f * (3.0f * z * z - 1.0f), s3 * x * z);
    shp[2] = make_float4(0.5f * s3 * (x * x - y * y), __int_as_float(snd), 0.f, 0.f);

    float xx = r * 0.2f;
    float env = 0.0f;
    if (xx < 1.0f) {
        float x2 = xx * xx;
        float x6 = x2 * x2 * x2;
        float x7 = x6 * xx;
        float x8 = x7 * xx;
        env = 1.0f - 28.0f * x6 + 48.0f * x7 - 21.0f * x8;
    }
    const float pref = 0.63245553f;  // sqrt(2/R_MAX)
    const float PI_F = 3.14159265358979f;
    float fac = pref * inv * env;
    float ef[NBb];
#pragma unroll
    for (int k = 0; k < NBb; k++)
        ef[k] = fac * __sinf((float)(k + 1) * PI_F * r * 0.2f);

    float acc[64];
#pragma unroll
    for (int c = 0; c < 64; c++) acc[c] = 0.0f;
    for (int j = 0; j < 64; j++) {
        float a = br1[j];
#pragma unroll
        for (int k = 0; k < NBb; k++) a += ef[k] * g_W1T[j * NBb + k];
        a = a * __builtin_amdgcn_rcpf(1.0f + __expf(-a));
        const float* __restrict__ w2 = Wr2 + j * 64;
#pragma unroll
        for (int c = 0; c < 64; c++) acc[c] += a * w2[c];
    }
    float* dst = g_R4 + (size_t)(s >> 2) * 256 + (s & 3);
#pragma unroll
    for (int c = 0; c < 64; c++) dst[c * 4] = acc[c];
}

__global__ __launch_bounds__(256) void k_hinit(const float* __restrict__ W_embed,
                                               const int* __restrict__ atom_types) {
    int i = blockIdx.x * 256 + threadIdx.x;
    if (i >= Nn * 64) return;
    int n = i >> 6, c = i & 63;
    g_h[0][i] = W_embed[atom_types[n] * 64 + c];
}

__global__ __launch_bounds__(256) void k_lin(const float* __restrict__ Wup,
                                             const float* __restrict__ Wsc, int l) {
    __shared__ float sU[4096];
    __shared__ float sS[4096];
    int t = threadIdx.x;
    for (int i = t; i < 4096; i += 256) { sU[i] = Wup[i]; sS[i] = Wsc[i]; }
    __syncthreads();
    int node = blockIdx.x * 4 + (t >> 6);
    int lane = t & 63;
    const float* hin = g_h[l & 1];
    float hv = hin[node * 64 + lane];
    float a1 = 0.0f, a2 = 0.0f;
#pragma unroll
    for (int k = 0; k < 64; k++) {
        float hk = __shfl(hv, k, 64);
        a1 += hk * sU[k * 64 + lane];
        a2 += hk * sS[k * 64 + lane];
    }
    g_h1[node * 64 + lane] = a1;
    g_hsc[node * 64 + lane] = a2;
}

// Tail-free 8-wide batches: 2 float4 R loads + 24 broadcast sh loads +
// 8 h1 gathers per batch, all independent once the sh-C quads arrive.
__global__ __launch_bounds__(256, 2) void k_node(const float* __restrict__ Wprod,
                                                 const float* __restrict__ wro,
                                                 const int* __restrict__ batch,
                                                 int l, float* __restrict__ out) {
    __shared__ float sP[4096];
    int t = threadIdx.x;
    for (int i = t; i < 4096; i += 256) sP[i] = Wprod[i];
    __syncthreads();
    int node = blockIdx.x * 4 + (t >> 6);
    int lane = t & 63;
    int beg = __builtin_amdgcn_readfirstlane(g_offs[node]);   // multiple of 8
    int deg = __builtin_amdgcn_readfirstlane(g_deg[node]);
    int nb = (deg + 7) >> 3;
    float A[9];
#pragma unroll
    for (int m = 0; m < 9; m++) A[m] = 0.0f;

    for (int b = 0; b < nb; b++) {
        int j = beg + b * 8;
        // phase 1: sh-C quads (carry src) for all 8 slots
        float4 shC[8];
#pragma unroll
        for (int k = 0; k < 8; k++)
            shC[k] = *(const float4*)(g_shc + (size_t)(j + k) * 12 + 8);
        // phase 2: h1 gathers (independent 8-wide after one indirection)
        float hv[8];
#pragma unroll
        for (int k = 0; k < 8; k++) {
            int src = __float_as_int(shC[k].y);
            hv[k] = g_h1[src * 64 + lane];
        }
        // phase 3: R (2 interleaved float4 = 8 slots) + sh-A/B quads
        float4 r0 = *(const float4*)(g_R4 + (size_t)(j >> 2) * 256 + lane * 4);
        float4 r1 = *(const float4*)(g_R4 + (size_t)((j >> 2) + 1) * 256 + lane * 4);
        float4 shA[8], shB[8];
#pragma unroll
        for (int k = 0; k < 8; k++) {
            const float4* p = (const float4*)(g_shc + (size_t)(j + k) * 12);
            shA[k] = p[0];
            shB[k] = p[1];
        }
        float rv[8] = {r0.x, r0.y, r0.z, r0.w, r1.x, r1.y, r1.z, r1.w};
#pragma unroll
        for (int k = 0; k < 8; k++) {
            float tv = rv[k] * hv[k];
            A[0] += shA[k].x * tv; A[1] += shA[k].y * tv;
            A[2] += shA[k].z * tv; A[3] += shA[k].w * tv;
            A[4] += shB[k].x * tv; A[5] += shB[k].y * tv;
            A[6] += shB[k].z * tv; A[7] += shB[k].w * tv;
            A[8] += shC[k].x * tv;
        }
    }

    const float invn = 1.0f / 16.0f;  // AVG_NEI
    float q = A[0] * invn;
#pragma unroll
    for (int m = 0; m < 9; m++) {
        float a = A[m] * invn;
        q += a * a;
    }
    float hn = g_hsc[node * 64 + lane];
#pragma unroll
    for (int k = 0; k < 64; k++) {
        float qk = __shfl(q, k, 64);
        hn += qk * sP[k * 64 + lane];
    }
    float* hout = g_h[(l + 1) & 1];
    hout[node * 64 + lane] = hn;
    float v = hn * wro[lane];
#pragma unroll
    for (int off = 32; off > 0; off >>= 1) v += __shfl_down(v, off, 64);
    if (lane == 0) atomicAdd(&out[batch[node]], v);
}

extern "C" void kernel_launch(void* const* d_in, const int* in_sizes, int n_in,
                              void* d_out, int out_size, void* d_ws, size_t ws_size,
                              hipStream_t stream) {
    const float* pos     = (const float*)d_in[0];
    const float* W_embed = (const float*)d_in[1];
    const float* W_r1    = (const float*)d_in[2];
    const float* b_r1    = (const float*)d_in[3];
    const float* W_r2    = (const float*)d_in[4];
    const float* W_up    = (const float*)d_in[5];
    const float* W_sc    = (const float*)d_in[6];
    const float* W_prod  = (const float*)d_in[7];
    const float* w_ro    = (const float*)d_in[8];
    const int* atom_types = (const int*)d_in[9];
    const int* eidx       = (const int*)d_in[10];
    const int* batch      = (const int*)d_in[11];
    float* out = (float*)d_out;

    k_zero<<<CSRMAX / 256, 256, 0, stream>>>(out, out_size);
    k_deg<<<Ee / 256, 256, 0, stream>>>(eidx, W_r1);
    k_scan<<<1, 1024, 0, stream>>>();
    k_fill<<<Ee / 256, 256, 0, stream>>>(eidx);
    k_edge<<<CSRMAX / 256, 256, 0, stream>>>(pos, b_r1, W_r2, eidx);
    k_hinit<<<(Nn * 64) / 256, 256, 0, stream>>>(W_embed, atom_types);
    for (int l = 0; l < 2; l++) {
        k_lin<<<Nn / 4, 256, 0, stream>>>(W_up + l * 4096, W_sc + l * 4096, l);
        k_node<<<Nn / 4, 256, 0, stream>>>(W_prod + l * 4096, w_ro + l * 64, batch, l, out);
    }
}